// Round 4
// baseline (1924.661 us; speedup 1.0000x reference)
//
#include <hip/hip_runtime.h>
#include <cstdint>
#include <cstddef>

typedef unsigned short u16;
typedef __attribute__((ext_vector_type(8))) short short8;
typedef __attribute__((ext_vector_type(4))) float f32x4;

#define BB 16
#define NT 1569
#define DIM 768
#define NH 12
#define HD 64
#define FR 8
#define NS 196
#define MROWS (BB*NT)   // 25104
#define NKEY 197

__device__ __forceinline__ float bf2f(u16 h) {
    return __uint_as_float(((unsigned int)h) << 16);
}
__device__ __forceinline__ u16 f2bf(float f) {
    unsigned int u = __float_as_uint(f);
    u += 0x7fff + ((u >> 16) & 1);   // RNE
    return (u16)(u >> 16);
}
__device__ __forceinline__ void gload_lds16(const u16* g, u16* l) {
    __builtin_amdgcn_global_load_lds(
        (const __attribute__((address_space(1))) void*)g,
        (__attribute__((address_space(3))) void*)l, 16, 0, 0);
}

// ---------------- LayerNorm: fp32/bf16 in -> bf16 out ----------------
template<bool IBF>
__global__ __launch_bounds__(256) void ln_kernel(const void* __restrict__ xin,
        const float* __restrict__ w, const float* __restrict__ b,
        u16* __restrict__ out) {
    int row = blockIdx.x;
    size_t base = (size_t)row * DIM;
    int tid = threadIdx.x;
    float v0, v1, v2;
    if (IBF) {
        const u16* x = (const u16*)xin;
        v0 = bf2f(x[base + tid]); v1 = bf2f(x[base + tid + 256]); v2 = bf2f(x[base + tid + 512]);
    } else {
        const float* x = (const float*)xin;
        v0 = x[base + tid]; v1 = x[base + tid + 256]; v2 = x[base + tid + 512];
    }
    float s = v0 + v1 + v2;
    float q = v0*v0 + v1*v1 + v2*v2;
    #pragma unroll
    for (int o = 32; o >= 1; o >>= 1) {
        s += __shfl_xor(s, o, 64);
        q += __shfl_xor(q, o, 64);
    }
    __shared__ float rs[4], rq[4];
    int wave = tid >> 6, lane = tid & 63;
    if (lane == 0) { rs[wave] = s; rq[wave] = q; }
    __syncthreads();
    float S = rs[0]+rs[1]+rs[2]+rs[3];
    float Q = rq[0]+rq[1]+rq[2]+rq[3];
    float mean = S * (1.0f/DIM);
    float var  = Q * (1.0f/DIM) - mean*mean;
    float inv  = rsqrtf(var + 1e-6f);
    out[base+tid]     = f2bf((v0-mean)*inv*w[tid]     + b[tid]);
    out[base+tid+256] = f2bf((v1-mean)*inv*w[tid+256] + b[tid+256]);
    out[base+tid+512] = f2bf((v2-mean)*inv*w[tid+512] + b[tid+512]);
}

// ------------- weight convert: fp32 [K,N] -> bf16 [N,K] -------------
__global__ __launch_bounds__(256) void wconv_kernel(const float* __restrict__ in,
        u16* __restrict__ out, int K, int N) {
    __shared__ float tile[32][33];
    int n0 = blockIdx.x * 32, k0 = blockIdx.y * 32;
    int tx = threadIdx.x & 31, ty = threadIdx.x >> 5;
    #pragma unroll
    for (int i = 0; i < 32; i += 8)
        tile[ty+i][tx] = in[(size_t)(k0+ty+i)*N + n0+tx];
    __syncthreads();
    #pragma unroll
    for (int i = 0; i < 32; i += 8)
        out[(size_t)(n0+ty+i)*K + k0+tx] = f2bf(tile[tx][ty+i]);
}

// ---------------- bf16 MFMA GEMM: C = A[M,K] * BT[N,K]^T ----------------
// TN: wave n-extent in 16-col units (4 -> BN=128, 8 -> BN=256). BK: K-tile.
// EPI: 0=+bias, 1=+bias+residual, 2=+bias+gelu. OBF: bf16 out. RBF: bf16 resid.
// global_load_lds width-16 staging; grouped-pid swizzle for L2/L3 A reuse.
template<int TN, int BK, int EPI, bool OBF, bool RBF>
__global__ __launch_bounds__(256) void gemm_kernel(
        const u16* __restrict__ A, const u16* __restrict__ BT,
        const float* __restrict__ bias, const void* __restrict__ resid,
        void* __restrict__ Cout, int M, int N, int K, int num_m, int num_n) {
    constexpr int BN = 32 * TN;
    constexpr int AI = BK / 16;           // A gload instrs per wave
    constexpr int BI = BN * BK / 2048;    // B gload instrs per wave
    __shared__ u16 lsA[128*BK];
    __shared__ u16 lsB[BN*BK];
    // grouped pid mapping
    const int GRP = 16;
    int pid = blockIdx.x;
    int gsz = GRP * num_n;
    int gid = pid / gsz;
    int rem = pid - gid*gsz;
    int m0b = gid * GRP;
    int msz = num_m - m0b; if (msz > GRP) msz = GRP;
    int pm = m0b + rem % msz;
    int pn = rem / msz;
    int row0 = pm * 128, col0 = pn * BN;
    int tid = threadIdx.x;
    int wave = tid >> 6, lane = tid & 63;
    int wm = (wave >> 1) * 64, wn = (wave & 1) * 16 * TN;
    int cb = lane & 15, quad = lane >> 4;
    // staging pointers: chunk of 1024 B = 512 u16, lane l covers elems l*8..l*8+7
    const u16* gAp[AI]; const u16* gBp[BI];
    u16* lA[AI]; u16* lB[BI];
    #pragma unroll
    for (int i = 0; i < AI; ++i) {
        int e = (wave*AI + i)*512 + lane*8;
        int r = e / BK, c = e % BK;
        int gr = row0 + r; if (gr > M-1) gr = M-1;   // clamp; stores guarded
        gAp[i] = A + (size_t)gr*K + c;
        lA[i] = &lsA[(wave*AI + i)*512];
    }
    #pragma unroll
    for (int i = 0; i < BI; ++i) {
        int e = (wave*BI + i)*512 + lane*8;
        int r = e / BK, c = e % BK;
        gBp[i] = BT + (size_t)(col0 + r)*K + c;
        lB[i] = &lsB[(wave*BI + i)*512];
    }
    f32x4 acc[4][TN] = {};
    for (int k0 = 0; k0 < K; k0 += BK) {
        #pragma unroll
        for (int i = 0; i < AI; ++i) gload_lds16(gAp[i] + k0, lA[i]);
        #pragma unroll
        for (int i = 0; i < BI; ++i) gload_lds16(gBp[i] + k0, lB[i]);
        __syncthreads();
        #pragma unroll
        for (int ks = 0; ks < BK/32; ++ks) {
            short8 af[4], bfr[TN];
            #pragma unroll
            for (int t = 0; t < 4; ++t)
                af[t] = *(const short8*)&lsA[(wm + t*16 + cb)*BK + ks*32 + quad*8];
            #pragma unroll
            for (int j = 0; j < TN; ++j)
                bfr[j] = *(const short8*)&lsB[(wn + j*16 + cb)*BK + ks*32 + quad*8];
            #pragma unroll
            for (int i = 0; i < 4; ++i)
                #pragma unroll
                for (int j = 0; j < TN; ++j)
                    acc[i][j] = __builtin_amdgcn_mfma_f32_16x16x32_bf16(af[i], bfr[j], acc[i][j], 0, 0, 0);
        }
        __syncthreads();
    }
    #pragma unroll
    for (int i = 0; i < 4; ++i) {
      #pragma unroll
      for (int j = 0; j < TN; ++j) {
        int gn = col0 + wn + j*16 + cb;
        float bv = bias[gn];
        #pragma unroll
        for (int r = 0; r < 4; ++r) {
            int gm = row0 + wm + i*16 + quad*4 + r;
            if (gm < M) {
                float v = acc[i][j][r] + bv;
                if (EPI == 1) {
                    size_t ridx = (size_t)gm*N + gn;
                    v += RBF ? bf2f(((const u16*)resid)[ridx]) : ((const float*)resid)[ridx];
                }
                if (EPI == 2) {
                    float z = 0.7978845608028654f*(v + 0.044715f*v*v*v);
                    float t = 1.0f - 2.0f/(__expf(2.0f*z) + 1.0f);   // tanh(z)
                    v = 0.5f*v*(1.0f + t);
                }
                if (OBF) ((u16*)Cout)[(size_t)gm*N + gn] = f2bf(v);
                else     ((float*)Cout)[(size_t)gm*N + gn] = v;
            }
        }
      }
    }
}

// ------------- cls attention phase 1: partial softmax over a key chunk -------------
// grid: (b, h, chunk c of 8).  part[bid] = {m, s, acc[64]} (66 floats)
__global__ __launch_bounds__(256) void attn_cls_part(const u16* __restrict__ qkv,
        float* __restrict__ part) {
    __shared__ float qf[64];
    __shared__ float p[256];
    __shared__ float red[4];
    __shared__ float pacc[4][64];
    int bid = blockIdx.x;
    int c = bid & 7; int h = (bid >> 3) % NH; int b = bid / (8*NH);
    size_t base = ((size_t)b*NT)*(3*DIM) + (size_t)h*HD;
    int k0 = c * 197;
    int nk = NT - k0; if (nk > 197) nk = 197;
    int tid = threadIdx.x;
    if (tid < 64) qf[tid] = bf2f(qkv[base + tid]);
    __syncthreads();
    float sc = -1e30f;
    if (tid < nk) {
        const u16* kp = qkv + base + (size_t)(k0 + tid)*(3*DIM) + DIM;
        float a0=0,a1=0,a2=0,a3=0;
        #pragma unroll
        for (int d = 0; d < 64; d += 4) {
            a0 += qf[d]  *bf2f(kp[d]);
            a1 += qf[d+1]*bf2f(kp[d+1]);
            a2 += qf[d+2]*bf2f(kp[d+2]);
            a3 += qf[d+3]*bf2f(kp[d+3]);
        }
        sc = (a0+a1+a2+a3)*0.125f;
    }
    float lmax = sc;
    #pragma unroll
    for (int o = 32; o >= 1; o >>= 1) lmax = fmaxf(lmax, __shfl_xor(lmax, o, 64));
    if ((tid&63) == 0) red[tid>>6] = lmax;
    __syncthreads();
    float m = fmaxf(fmaxf(red[0],red[1]), fmaxf(red[2],red[3]));
    float e = (tid < nk) ? __expf(sc - m) : 0.f;
    p[tid] = e;
    float lsum = e;
    #pragma unroll
    for (int o = 32; o >= 1; o >>= 1) lsum += __shfl_xor(lsum, o, 64);
    __syncthreads();
    if ((tid&63) == 0) red[tid>>6] = lsum;
    __syncthreads();
    float s = red[0]+red[1]+red[2]+red[3];
    int d = tid & 63, g = tid >> 6;
    float a = 0.f;
    for (int kk = g; kk < nk; kk += 4)
        a += p[kk]*bf2f(qkv[base + (size_t)(k0+kk)*(3*DIM) + 2*DIM + d]);
    pacc[g][d] = a;
    __syncthreads();
    float* pc = part + (size_t)bid*66;
    if (tid == 0) { pc[0] = m; pc[1] = s; }
    if (tid < 64)
        pc[2+tid] = pacc[0][tid]+pacc[1][tid]+pacc[2][tid]+pacc[3][tid];
}

// ------------- cls attention phase 2: merge 8 partials -------------
__global__ __launch_bounds__(64) void attn_cls_merge(const float* __restrict__ part,
        u16* __restrict__ out) {
    int bid = blockIdx.x;       // b*NH + h
    int b = bid / NH, h = bid % NH;
    int tid = threadIdx.x;      // d
    const float* pc = part + (size_t)bid*8*66;
    float mstar = -1e30f;
    #pragma unroll
    for (int c = 0; c < 8; ++c) mstar = fmaxf(mstar, pc[c*66]);
    float S = 0.f, O = 0.f;
    #pragma unroll
    for (int c = 0; c < 8; ++c) {
        float al = __expf(pc[c*66] - mstar);
        S += pc[c*66 + 1] * al;
        O += pc[c*66 + 2 + tid] * al;
    }
    out[((size_t)b*NT)*DIM + h*HD + tid] = f2bf(O / S);
}

// ------------- time attention: one block per (b,h,n); 8 q x 9 kv -------------
__global__ __launch_bounds__(256) void attn_time_kernel(const u16* __restrict__ qkv,
        u16* __restrict__ out) {
    __shared__ float qs[8][68], ks[9][68], vs[9][68];
    __shared__ float pr[8][12];
    int bid = blockIdx.x;
    int n = bid % NS; int rem = bid / NS; int h = rem % NH; int b = rem / NH;
    size_t base = ((size_t)b*NT)*(3*DIM) + h*HD;
    int tid = threadIdx.x;
    for (int idx = tid; idx < 512; idx += 256) {
        int f = idx >> 6, d = idx & 63;
        int tok = 1 + f*NS + n;
        size_t p = base + (size_t)tok*(3*DIM) + d;
        qs[f][d]   = bf2f(qkv[p]);
        ks[f+1][d] = bf2f(qkv[p + DIM]);
        vs[f+1][d] = bf2f(qkv[p + 2*DIM]);
    }
    if (tid < 64) {
        ks[0][tid] = bf2f(qkv[base + DIM + tid]);
        vs[0][tid] = bf2f(qkv[base + 2*DIM + tid]);
    }
    __syncthreads();
    if (tid < 72) {
        int fq = tid / 9, kk = tid % 9;
        float a0=0,a1=0,a2=0,a3=0;
        #pragma unroll
        for (int d = 0; d < 64; d += 4) {
            a0 += qs[fq][d]  *ks[kk][d];
            a1 += qs[fq][d+1]*ks[kk][d+1];
            a2 += qs[fq][d+2]*ks[kk][d+2];
            a3 += qs[fq][d+3]*ks[kk][d+3];
        }
        pr[fq][kk] = (a0+a1+a2+a3)*0.125f;
    }
    __syncthreads();
    if (tid < 8) {
        float m = -1e30f;
        #pragma unroll
        for (int kk = 0; kk < 9; ++kk) m = fmaxf(m, pr[tid][kk]);
        float sum = 0.f;
        #pragma unroll
        for (int kk = 0; kk < 9; ++kk) { float e = __expf(pr[tid][kk]-m); pr[tid][kk] = e; sum += e; }
        float inv = 1.0f/sum;
        #pragma unroll
        for (int kk = 0; kk < 9; ++kk) pr[tid][kk] *= inv;
    }
    __syncthreads();
    for (int idx = tid; idx < 512; idx += 256) {
        int fq = idx >> 6, d = idx & 63;
        float a = 0.f;
        #pragma unroll
        for (int kk = 0; kk < 9; ++kk) a += pr[fq][kk]*vs[kk][d];
        int tok = 1 + fq*NS + n;
        out[((size_t)b*NT + tok)*DIM + h*HD + d] = f2bf(a);
    }
}

// ------------- space attention (MFMA): one block per (b,h,f) -------------
#define VSTR 232
__global__ __launch_bounds__(256, 2) void attn_space_kernel(const u16* __restrict__ qkv,
        u16* __restrict__ out) {
    __shared__ u16 VT[64*VSTR];        // [d][key], cols 197..231 zero
    __shared__ u16 Ps[4][16*VSTR];     // per-wave P[qrow][key], cols 208..231 zero
    int bid = blockIdx.x;
    int b = bid / (NH*FR); int rem = bid % (NH*FR); int h = rem / FR; int f = rem % FR;
    size_t base = ((size_t)b*NT)*(3*DIM) + (size_t)h*HD;
    int tid = threadIdx.x;
    int wave = tid >> 6, lane = tid & 63;
    int cb = lane & 15, quad = lane >> 4;

    for (int idx = tid; idx < NKEY*64; idx += 256) {
        int d = idx / NKEY, key = idx - d*NKEY;
        int tok = (key == 0) ? 0 : (1 + f*NS + key - 1);
        VT[d*VSTR + key] = qkv[base + (size_t)tok*(3*DIM) + 2*DIM + d];
    }
    for (int idx = tid; idx < 64*(VSTR-NKEY); idx += 256) {
        int d = idx / (VSTR-NKEY), c = idx - d*(VSTR-NKEY);
        VT[d*VSTR + NKEY + c] = 0;
    }
    for (int idx = tid; idx < 4*16*(VSTR-208); idx += 256) {
        int r = idx / (VSTR-208), c = idx - r*(VSTR-208);
        ((u16*)Ps)[r*VSTR + 208 + c] = 0;
    }
    __syncthreads();

    for (int qt = wave; qt < 13; qt += 4) {
        int q0 = qt*16;
        int qrow = q0 + cb; if (qrow > 195) qrow = 195;
        const u16* qp = qkv + base + (size_t)(1 + f*NS + qrow)*(3*DIM);
        short8 a0 = *(const short8*)(qp + quad*8);
        short8 a1 = *(const short8*)(qp + 32 + quad*8);
        f32x4 sacc[13];
        #pragma unroll
        for (int kt = 0; kt < 13; ++kt) {
            int key = kt*16 + cb; if (key > 196) key = 196;
            int ktok = (key == 0) ? 0 : (1 + f*NS + key - 1);
            const u16* kp = qkv + base + (size_t)ktok*(3*DIM) + DIM;
            short8 b0 = *(const short8*)(kp + quad*8);
            short8 b1 = *(const short8*)(kp + 32 + quad*8);
            f32x4 z = {0.f, 0.f, 0.f, 0.f};
            z = __builtin_amdgcn_mfma_f32_16x16x32_bf16(a0, b0, z, 0, 0, 0);
            z = __builtin_amdgcn_mfma_f32_16x16x32_bf16(a1, b1, z, 0, 0, 0);
            sacc[kt] = z;
        }
        bool last_ok = (cb < 5);
        float mx[4] = {-1e30f, -1e30f, -1e30f, -1e30f};
        #pragma unroll
        for (int kt = 0; kt < 13; ++kt) {
            bool ok = (kt < 12) || last_ok;
            #pragma unroll
            for (int r = 0; r < 4; ++r) {
                float v = sacc[kt][r] * 0.125f;
                sacc[kt][r] = v;
                if (ok) mx[r] = fmaxf(mx[r], v);
            }
        }
        #pragma unroll
        for (int off = 1; off < 16; off <<= 1)
            #pragma unroll
            for (int r = 0; r < 4; ++r)
                mx[r] = fmaxf(mx[r], __shfl_xor(mx[r], off, 64));
        float sum[4] = {0.f, 0.f, 0.f, 0.f};
        u16* prow = &Ps[wave][0];
        #pragma unroll
        for (int kt = 0; kt < 13; ++kt) {
            bool ok = (kt < 12) || last_ok;
            #pragma unroll
            for (int r = 0; r < 4; ++r) {
                float e = ok ? __expf(sacc[kt][r] - mx[r]) : 0.f;
                sum[r] += e;
                prow[(quad*4 + r)*VSTR + kt*16 + cb] = f2bf(e);
            }
        }
        #pragma unroll
        for (int off = 1; off < 16; off <<= 1)
            #pragma unroll
            for (int r = 0; r < 4; ++r)
                sum[r] += __shfl_xor(sum[r], off, 64);
        short8 pf[7];
        #pragma unroll
        for (int ks = 0; ks < 7; ++ks)
            pf[ks] = *(const short8*)&Ps[wave][cb*VSTR + ks*32 + quad*8];
        f32x4 oacc[4];
        #pragma unroll
        for (int nt = 0; nt < 4; ++nt) {
            f32x4 z = {0.f, 0.f, 0.f, 0.f};
            #pragma unroll
            for (int ks = 0; ks < 7; ++ks) {
                short8 vf = *(const short8*)&VT[(nt*16 + cb)*VSTR + ks*32 + quad*8];
                z = __builtin_amdgcn_mfma_f32_16x16x32_bf16(pf[ks], vf, z, 0, 0, 0);
            }
            oacc[nt] = z;
        }
        float inv[4];
        #pragma unroll
        for (int r = 0; r < 4; ++r) inv[r] = 1.0f / sum[r];
        #pragma unroll
        for (int r = 0; r < 4; ++r) {
            int qr = q0 + quad*4 + r;
            if (qr < 196) {
                size_t orow = ((size_t)b*NT + 1 + (size_t)f*NS + qr)*DIM + (size_t)h*HD;
                #pragma unroll
                for (int nt = 0; nt < 4; ++nt)
                    out[orow + nt*16 + cb] = f2bf(oacc[nt][r] * inv[r]);
            }
        }
    }
}

// ---------------------------------------------------------------------------
extern "C" void kernel_launch(void* const* d_in, const int* in_sizes, int n_in,
                              void* d_out, int out_size, void* d_ws, size_t ws_size,
                              hipStream_t stream) {
    const float* x          = (const float*)d_in[0];
    const float* norm1_w    = (const float*)d_in[1];
    const float* norm1_b    = (const float*)d_in[2];
    const float* norm2_w    = (const float*)d_in[3];
    const float* norm2_b    = (const float*)d_in[4];
    const float* norm3_w    = (const float*)d_in[5];
    const float* norm3_b    = (const float*)d_in[6];
    const float* t_qkv_w    = (const float*)d_in[7];
    const float* t_qkv_b    = (const float*)d_in[8];
    const float* t_proj_w   = (const float*)d_in[9];
    const float* t_proj_b   = (const float*)d_in[10];
    const float* s_qkv_w    = (const float*)d_in[11];
    const float* s_qkv_b    = (const float*)d_in[12];
    const float* s_proj_w   = (const float*)d_in[13];
    const float* s_proj_b   = (const float*)d_in[14];
    const float* mlp_w1     = (const float*)d_in[15];
    const float* mlp_b1     = (const float*)d_in[16];
    const float* mlp_w2     = (const float*)d_in[17];
    const float* mlp_b2     = (const float*)d_in[18];
    float* out = (float*)d_out;

    // workspace layout (bytes)
    char* ws = (char*)d_ws;
    const size_t M = MROWS;
    u16*  qkv  = (u16*)(ws);                          // M*2304 bf16
    u16*  attn = (u16*)(ws + M*2304*2);               // M*768 bf16
    u16*  hbuf = (u16*)(ws);                          // M*3072 bf16 (overlays qkv+attn)
    u16*  xn   = (u16*)(ws + M*3072*2);               // M*768 bf16
    u16*  x1   = (u16*)(ws + M*3072*2 + M*768*2);     // M*768 bf16 (t-branch residual)
    float* clsp = (float*)(ws + M*3072*2 + M*768*2 + M*768*2);  // 1536*66 fp32 (upper half of old x1 slot)
    char* wsp  = ws + M*3072*2 + M*768*2 + M*768*4;
    u16* wqT_t = (u16*)(wsp);                 wsp += 2304*768*2;
    u16* wqT_s = (u16*)(wsp);                 wsp += 2304*768*2;
    u16* wpT_t = (u16*)(wsp);                 wsp += 768*768*2;
    u16* wpT_s = (u16*)(wsp);                 wsp += 768*768*2;
    u16* w1T   = (u16*)(wsp);                 wsp += 3072*768*2;
    u16* w2T   = (u16*)(wsp);

    // ---- weight conversion (transpose to [N,K] bf16) ----
    wconv_kernel<<<dim3(2304/32, 768/32), 256, 0, stream>>>(t_qkv_w, wqT_t, 768, 2304);
    wconv_kernel<<<dim3(2304/32, 768/32), 256, 0, stream>>>(s_qkv_w, wqT_s, 768, 2304);
    wconv_kernel<<<dim3(768/32, 768/32), 256, 0, stream>>>(t_proj_w, wpT_t, 768, 768);
    wconv_kernel<<<dim3(768/32, 768/32), 256, 0, stream>>>(s_proj_w, wpT_s, 768, 768);
    wconv_kernel<<<dim3(3072/32, 768/32), 256, 0, stream>>>(mlp_w1, w1T, 768, 3072);
    wconv_kernel<<<dim3(768/32, 3072/32), 256, 0, stream>>>(mlp_w2, w2T, 3072, 768);

    const int GM = (MROWS + 127) / 128;   // 197

    // ---- time attention branch ----
    ln_kernel<false><<<MROWS, 256, 0, stream>>>(x, norm3_w, norm3_b, xn);
    gemm_kernel<8, 64, 0, true, false><<<GM*(2304/256), 256, 0, stream>>>(xn, wqT_t, t_qkv_b, nullptr, qkv, MROWS, 2304, 768, GM, 2304/256);
    attn_cls_part <<<BB*NH*8, 256, 0, stream>>>(qkv, clsp);
    attn_cls_merge<<<BB*NH, 64, 0, stream>>>(clsp, attn);
    attn_time_kernel<<<BB*NH*NS, 256, 0, stream>>>(qkv, attn);
    gemm_kernel<4, 64, 1, true, false><<<GM*(768/128), 256, 0, stream>>>(attn, wpT_t, t_proj_b, x, x1, MROWS, 768, 768, GM, 768/128);

    // ---- space attention branch ----
    ln_kernel<true><<<MROWS, 256, 0, stream>>>(x1, norm1_w, norm1_b, xn);
    gemm_kernel<8, 64, 0, true, false><<<GM*(2304/256), 256, 0, stream>>>(xn, wqT_s, s_qkv_b, nullptr, qkv, MROWS, 2304, 768, GM, 2304/256);
    attn_cls_part <<<BB*NH*8, 256, 0, stream>>>(qkv, clsp);
    attn_cls_merge<<<BB*NH, 64, 0, stream>>>(clsp, attn);
    attn_space_kernel<<<BB*NH*FR, 256, 0, stream>>>(qkv, attn);
    gemm_kernel<4, 64, 1, false, true><<<GM*(768/128), 256, 0, stream>>>(attn, wpT_s, s_proj_b, x1, out, MROWS, 768, 768, GM, 768/128);

    // ---- MLP ----
    ln_kernel<false><<<MROWS, 256, 0, stream>>>(out, norm2_w, norm2_b, xn);
    gemm_kernel<8, 64, 2, true, false><<<GM*(3072/256), 256, 0, stream>>>(xn, w1T, mlp_b1, nullptr, hbuf, MROWS, 3072, 768, GM, 3072/256);
    gemm_kernel<4, 64, 1, false, false><<<GM*(768/128), 256, 0, stream>>>(hbuf, w2T, mlp_b2, out, out, MROWS, 768, 3072, GM, 768/128);
}